// Round 6
// baseline (100.939 us; speedup 1.0000x reference)
//
#include <hip/hip_runtime.h>

typedef short short8 __attribute__((ext_vector_type(8)));
typedef float f32x4  __attribute__((ext_vector_type(4)));

// Problem dims
constexpr int N_    = 256;
constexpr int T_    = 2048;
constexpr int V_    = 9;
constexpr int FIN_  = 144;      // K dim of stage-1 GEMM
constexpr int J_    = 27;       // output cols (w*3 + o)
constexpr int KT_   = 9;
constexpr int THREADS_ = 128;   // 2 waves
constexpr int TILE_  = 120;     // output rows per tile
constexpr int NTILE_ = 18;      // tiles per n (18*120 = 2160 >= 2048; last tile 8 rows)
constexpr int CHUNK_ = 3;       // tiles per block (pipelined)
constexpr int BLKPN_ = NTILE_ / CHUNK_;   // 6 blocks per n
constexpr int ZROWS_ = 128;     // z rows per tile (TILE_+8)
constexpr int ZS_    = 28;      // z row stride floats (16B-aligned; b128 reads hit LDS BW floor)

// ws layout (float units)
constexpr int BF_OFF_F = 0;      // B-frags: 5120 bf16 (2560 floats)
constexpr int B0_OFF   = 2560;   // B0[27]
constexpr int WT_OFF   = 2587;   // Wt[o][o2][dd] (81)
constexpr int BT_OFF   = 2668;   // b_tcn[3]

__device__ __forceinline__ unsigned short bf16_rne(float x) {
    unsigned u = __float_as_uint(x);
    u = (u + 0x7FFFu + ((u >> 16) & 1u)) >> 16;
    return (unsigned short)u;
}
__device__ __forceinline__ unsigned pk2(float a, float b) {
    return (unsigned)bf16_rne(a) | ((unsigned)bf16_rne(b) << 16);
}

__global__ void setup_weights(const float* __restrict__ A,
                              const float* __restrict__ Wg,
                              const float* __restrict__ bg,
                              const float* __restrict__ Wt_in,
                              const float* __restrict__ bt,
                              float* __restrict__ ws) {
    __shared__ float Wc[FIN_ * J_];   // [k=f][n=j]
    const int tid = threadIdx.x;
    for (int idx = tid; idx < FIN_ * J_; idx += 256) {
        const int f = idx / J_, j = idx % J_;
        const int v = f >> 4, c = f & 15;
        const int w = j / 3, o = j % 3;
        float s = 0.f;
        #pragma unroll
        for (int k = 0; k < 5; ++k)
            s += Wg[(k * 3 + o) * 16 + c] * A[(k * 9 + v) * 9 + w];
        Wc[idx] = s;
    }
    __syncthreads();
    // B-fragments for mfma_f32_16x16x32_bf16: elem e of lane: (k=s*32+(l>>4)*8+e, n=nt*16+(l&15))
    unsigned short* bfp = (unsigned short*)(ws + BF_OFF_F);
    for (int i = tid; i < 5120; i += 256) {
        const int e = i & 7, lane = (i >> 3) & 63, nt = (i >> 9) & 1, s = i >> 10;
        const int k = s * 32 + (lane >> 4) * 8 + e;
        const int n = nt * 16 + (lane & 15);
        const float val = (k < FIN_ && n < J_) ? Wc[k * J_ + n] : 0.f;
        bfp[i] = bf16_rne(val);
    }
    if (tid < J_) {
        const int w = tid / 3, o = tid % 3;
        float s = 0.f;
        #pragma unroll
        for (int k = 0; k < 5; ++k) {
            float cs = 0.f;
            #pragma unroll
            for (int v = 0; v < V_; ++v) cs += A[(k * 9 + v) * 9 + w];
            s += bg[k * 3 + o] * cs;
        }
        ws[B0_OFF + tid] = s;
    }
    // Wt[o][o2][dd] = W_tcn[(o2*3+o)*9 + (8-dd)]  (conv_transpose: flip + I/O swap)
    if (tid < 81) {
        const int o = tid / 27, r = tid % 27, o2 = r / 9, dd = r % 9;
        ws[WT_OFF + tid] = Wt_in[(o2 * 3 + o) * 9 + (8 - dd)];
    }
    if (tid < 3) ws[BT_OFF + tid] = bt[tid];
}

__global__ __launch_bounds__(THREADS_, 2) void fused_stgcn(const float* __restrict__ pose,
                                                           const float* __restrict__ cw,
                                                           float* __restrict__ out) {
    __shared__ __align__(16) float zbuf[ZROWS_ * ZS_];   // 14336 B

    const int tid  = threadIdx.x;
    const int bid  = blockIdx.x;
    const int nb   = bid / BLKPN_;
    const int c0   = (bid % BLKPN_) * CHUNK_;            // first tile index of this block
    const int lane = tid & 63;
    const int wv   = tid >> 6;          // 0..1
    const int g8   = lane >> 4;
    const int j0   = lane & 15;
    const size_t nrow0 = (size_t)nb * T_;

    // LDS-only barrier: waits ds ops, leaves global loads in flight (vs __syncthreads's vmcnt(0))
    auto WB = []() {
        asm volatile("s_waitcnt lgkmcnt(0)" ::: "memory");
        __builtin_amdgcn_s_barrier();
    };

    // B-fragments -> registers (40 VGPRs)
    short8 bfrag[5][2];
    {
        const short8* bsrc = (const short8*)(cw + BF_OFF_F);
        #pragma unroll
        for (int s = 0; s < 5; ++s)
            #pragma unroll
            for (int nt = 0; nt < 2; ++nt)
                bfrag[s][nt] = bsrc[(s * 2 + nt) * 64 + lane];
    }
    const float b0n0 = cw[B0_OFF + j0];
    const float b0n1 = (j0 < 11) ? cw[B0_OFF + 16 + j0] : 0.f;

    auto issue = [&](int t0, int mt, float4* Av, float4* Bv) {
        const int text = t0 - 4 + wv * 64 + mt * 16 + j0;
        const bool okr = (text >= 0 && text < T_);
        const float* rowp = pose + (nrow0 + (okr ? text : 0)) * FIN_;
        #pragma unroll
        for (int s = 0; s < 5; ++s) {
            const int k0 = s * 32 + g8 * 8;
            const bool ok = okr && (k0 < FIN_);
            Av[s] = ok ? *(const float4*)(rowp + k0)     : make_float4(0.f, 0.f, 0.f, 0.f);
            Bv[s] = ok ? *(const float4*)(rowp + k0 + 4) : make_float4(0.f, 0.f, 0.f, 0.f);
        }
    };
    auto process = [&](int t0, int mt, const float4* Av, const float4* Bv) {
        short8 af[5];
        #pragma unroll
        for (int s = 0; s < 5; ++s) {
            union { unsigned u[4]; short8 s8; } cvu;
            cvu.u[0] = pk2(Av[s].x, Av[s].y);
            cvu.u[1] = pk2(Av[s].z, Av[s].w);
            cvu.u[2] = pk2(Bv[s].x, Bv[s].y);
            cvu.u[3] = pk2(Bv[s].z, Bv[s].w);
            af[s] = cvu.s8;
        }
        f32x4 acc0 = {0.f, 0.f, 0.f, 0.f};
        f32x4 acc1 = {0.f, 0.f, 0.f, 0.f};
        #pragma unroll
        for (int s = 0; s < 5; ++s) {
            acc0 = __builtin_amdgcn_mfma_f32_16x16x32_bf16(af[s], bfrag[s][0], acc0, 0, 0, 0);
            acc1 = __builtin_amdgcn_mfma_f32_16x16x32_bf16(af[s], bfrag[s][1], acc1, 0, 0, 0);
        }
        // D layout: col = lane&15, row = (lane>>4)*4 + reg
        #pragma unroll
        for (int r = 0; r < 4; ++r) {
            const int zrow = wv * 64 + mt * 16 + g8 * 4 + r;
            const int text = t0 - 4 + zrow;
            const bool okz = (text >= 0 && text < T_);
            zbuf[zrow * ZS_ + j0] = okz ? acc0[r] + b0n0 : 0.f;
            if (j0 < 11)
                zbuf[zrow * ZS_ + 16 + j0] = okz ? acc1[r] + b0n1 : 0.f;
        }
    };

    float4 A0v[5], B0v[5], A1v[5], B1v[5];
    int t0 = c0 * TILE_;
    issue(t0, 0, A0v, B0v);
    issue(t0, 1, A1v, B1v);

    #pragma unroll 1
    for (int i = 0; i < CHUNK_; ++i) {
        const int t0n = t0 + TILE_;
        const bool more = (i + 1 < CHUNK_);

        process(t0, 0, A0v, B0v);  issue(t0, 2, A0v, B0v);
        process(t0, 1, A1v, B1v);  issue(t0, 3, A1v, B1v);
        process(t0, 2, A0v, B0v);  if (more) issue(t0n, 0, A0v, B0v);
        process(t0, 3, A1v, B1v);  if (more) issue(t0n, 1, A1v, B1v);
        WB();   // z(i) ready; next-tile loads remain in flight

        // ---- Stage 2: temporal 9-tap mix + bias + leaky relu ----
        const int rows_out = min(TILE_, T_ - t0);
        float oacc[J_];
        if (tid < rows_out) {
            #pragma unroll
            for (int w = 0; w < V_; ++w)
                #pragma unroll
                for (int o2 = 0; o2 < 3; ++o2)
                    oacc[w * 3 + o2] = cw[BT_OFF + o2];
            #pragma unroll
            for (int dd = 0; dd < KT_; ++dd) {
                union { f32x4 v4[7]; float f[28]; } zu;
                const f32x4* zp = (const f32x4*)&zbuf[(tid + dd) * ZS_];
                #pragma unroll
                for (int c = 0; c < 7; ++c) zu.v4[c] = zp[c];
                #pragma unroll
                for (int o = 0; o < 3; ++o) {
                    #pragma unroll
                    for (int o2 = 0; o2 < 3; ++o2) {
                        const float wt = cw[WT_OFF + o * 27 + o2 * 9 + dd];
                        #pragma unroll
                        for (int w = 0; w < V_; ++w)
                            oacc[w * 3 + o2] = fmaf(zu.f[w * 3 + o], wt, oacc[w * 3 + o2]);
                    }
                }
            }
            #pragma unroll
            for (int j = 0; j < J_; ++j) oacc[j] = fmaxf(oacc[j], 0.01f * oacc[j]);
        }
        WB();   // stage-2 reads of zbuf complete
        if (tid < rows_out) {
            #pragma unroll
            for (int j = 0; j < J_; ++j) zbuf[tid * J_ + j] = oacc[j];
        }
        WB();   // repack visible

        const int total4 = (rows_out * J_) / 4;   // 810 or 54
        float4* dst4 = (float4*)(out + (nrow0 + t0) * J_);
        const float4* src4 = (const float4*)zbuf;
        for (int idx = tid; idx < total4; idx += THREADS_)
            dst4[idx] = src4[idx];
        WB();   // store's LDS reads complete before next tile's z-writes

        t0 = t0n;
    }
}

extern "C" void kernel_launch(void* const* d_in, const int* in_sizes, int n_in,
                              void* d_out, int out_size, void* d_ws, size_t ws_size,
                              hipStream_t stream) {
    const float* pose = (const float*)d_in[0];
    const float* A    = (const float*)d_in[1];
    const float* Wg   = (const float*)d_in[2];
    const float* bg   = (const float*)d_in[3];
    const float* Wt   = (const float*)d_in[4];
    const float* bt   = (const float*)d_in[5];
    float* ws   = (float*)d_ws;
    float* outp = (float*)d_out;

    setup_weights<<<1, 256, 0, stream>>>(A, Wg, bg, Wt, bt, ws);
    fused_stgcn<<<N_ * BLKPN_, THREADS_, 0, stream>>>(pose, ws, outp);
}

// Round 7
// 87.694 us; speedup vs baseline: 1.1510x; 1.1510x over previous
//
#include <hip/hip_runtime.h>

typedef short short8 __attribute__((ext_vector_type(8)));
typedef float f32x4  __attribute__((ext_vector_type(4)));

// Problem dims
constexpr int N_    = 256;
constexpr int T_    = 2048;
constexpr int V_    = 9;
constexpr int FIN_  = 144;      // K dim of stage-1 GEMM
constexpr int J_    = 27;       // output cols (w*3 + o)
constexpr int KT_   = 9;
constexpr int THREADS_ = 256;   // 4 waves
constexpr int TILE_  = 248;     // output rows per block
constexpr int NTILE_ = 9;
constexpr int XSTRIDE_B = 336;              // bf16 row stride: 168 bf16 = 84 words (2-way banks, free)
constexpr int XBUF_B  = 64 * XSTRIDE_B;     // 21504 B (one 64-row phase tile)
constexpr int ZROWS_  = 256;
constexpr int ZS_     = 28;                 // 112B; b128 reads -> 8/bank uniform = conflict-free min
constexpr int SMEM_B  = XBUF_B + ZROWS_ * ZS_ * 4;   // 50176 B -> 3 blocks/CU

// ws layout (float units)
constexpr int BF_OFF_F = 0;      // B-frags: 5120 bf16 (2560 floats)
constexpr int B0_OFF   = 2560;   // B0[27]
constexpr int WT_OFF   = 2587;   // Wt[o][o2][dd] (81)
constexpr int BT_OFF   = 2668;   // b_tcn[3]

__device__ __forceinline__ unsigned short bf16_rne(float x) {
    unsigned u = __float_as_uint(x);
    u = (u + 0x7FFFu + ((u >> 16) & 1u)) >> 16;
    return (unsigned short)u;
}
__device__ __forceinline__ unsigned pk2(float a, float b) {
    return (unsigned)bf16_rne(a) | ((unsigned)bf16_rne(b) << 16);
}

__global__ void setup_weights(const float* __restrict__ A,
                              const float* __restrict__ Wg,
                              const float* __restrict__ bg,
                              const float* __restrict__ Wt_in,
                              const float* __restrict__ bt,
                              float* __restrict__ ws) {
    __shared__ float Wc[FIN_ * J_];   // [k=f][n=j]
    const int tid = threadIdx.x;
    for (int idx = tid; idx < FIN_ * J_; idx += 256) {
        const int f = idx / J_, j = idx % J_;
        const int v = f >> 4, c = f & 15;
        const int w = j / 3, o = j % 3;
        float s = 0.f;
        #pragma unroll
        for (int k = 0; k < 5; ++k)
            s += Wg[(k * 3 + o) * 16 + c] * A[(k * 9 + v) * 9 + w];
        Wc[idx] = s;
    }
    __syncthreads();
    // B-fragments for mfma_f32_16x16x32_bf16: elem e of lane: (k=s*32+(l>>4)*8+e, n=nt*16+(l&15))
    unsigned short* bfp = (unsigned short*)(ws + BF_OFF_F);
    for (int i = tid; i < 5120; i += 256) {
        const int e = i & 7, lane = (i >> 3) & 63, nt = (i >> 9) & 1, s = i >> 10;
        const int k = s * 32 + (lane >> 4) * 8 + e;
        const int n = nt * 16 + (lane & 15);
        const float val = (k < FIN_ && n < J_) ? Wc[k * J_ + n] : 0.f;
        bfp[i] = bf16_rne(val);
    }
    if (tid < J_) {
        const int w = tid / 3, o = tid % 3;
        float s = 0.f;
        #pragma unroll
        for (int k = 0; k < 5; ++k) {
            float cs = 0.f;
            #pragma unroll
            for (int v = 0; v < V_; ++v) cs += A[(k * 9 + v) * 9 + w];
            s += bg[k * 3 + o] * cs;
        }
        ws[B0_OFF + tid] = s;
    }
    // Wt[o][o2][dd] = W_tcn[(o2*3+o)*9 + (8-dd)]  (conv_transpose: flip + I/O swap)
    if (tid < 81) {
        const int o = tid / 27, r = tid % 27, o2 = r / 9, dd = r % 9;
        ws[WT_OFF + tid] = Wt_in[(o2 * 3 + o) * 9 + (8 - dd)];
    }
    if (tid < 3) ws[BT_OFF + tid] = bt[tid];
}

__global__ __launch_bounds__(THREADS_, 3) void fused_stgcn(const float* __restrict__ pose,
                                                           const float* __restrict__ cw,
                                                           float* __restrict__ out) {
    __shared__ __align__(16) unsigned char smem[SMEM_B];
    float* zbuf = (float*)(smem + XBUF_B);

    const int tid  = threadIdx.x;
    const int bid  = blockIdx.x;
    const int nb   = bid / NTILE_;
    const int tile = bid % NTILE_;
    const int t0   = tile * TILE_;
    const int lane = tid & 63;
    const int wv   = tid >> 6;
    const int g8   = lane >> 4;
    const int j0   = lane & 15;
    const size_t nrow0 = (size_t)nb * T_;

    // LDS-only barrier: global loads stay in flight (vs __syncthreads's vmcnt(0) drain)
    auto WB = []() {
        asm volatile("s_waitcnt lgkmcnt(0)" ::: "memory");
        __builtin_amdgcn_s_barrier();
        asm volatile("" ::: "memory");
    };

    // issue phase-h loads: one CONTIGUOUS 36864B region, 9 coalesced float4/lane (4KB seq per instr)
    auto issue = [&](int h, float4* ld) {
        #pragma unroll
        for (int q = 0; q < 9; ++q) {
            const int fidx = q * THREADS_ + tid;
            const int r = fidx / 36, c4 = fidx % 36;
            const int text = t0 - 4 + h * 64 + r;
            const bool ok = (text >= 0 && text < T_);
            const float* p = pose + (nrow0 + (size_t)(ok ? text : 0)) * FIN_ + c4 * 4;
            ld[q] = ok ? *(const float4*)p : make_float4(0.f, 0.f, 0.f, 0.f);
        }
    };
    // convert + LDS write (waits that phase's vmcnt internally; next phase's loads already issued)
    auto stage = [&](const float4* ld) {
        #pragma unroll
        for (int q = 0; q < 9; ++q) {
            const int fidx = q * THREADS_ + tid;
            const int r = fidx / 36, c4 = fidx % 36;
            uint2 u;
            u.x = pk2(ld[q].x, ld[q].y);
            u.y = pk2(ld[q].z, ld[q].w);
            *(uint2*)(smem + r * XSTRIDE_B + c4 * 8) = u;
        }
    };

    float4 lda[9], ldb[9];
    issue(0, lda);

    // k-pad bytes [288,320) of each staged row must be zero (s=4 frag tail); written once
    for (int i = tid; i < 512; i += THREADS_) {
        const int r = i >> 3, w = i & 7;
        *(float*)(smem + r * XSTRIDE_B + 288 + w * 4) = 0.f;
    }
    // B-fragments -> registers (40 VGPRs), L2-resident
    short8 bfrag[5][2];
    {
        const short8* bsrc = (const short8*)(cw + BF_OFF_F);
        #pragma unroll
        for (int s = 0; s < 5; ++s)
            #pragma unroll
            for (int nt = 0; nt < 2; ++nt)
                bfrag[s][nt] = bsrc[(s * 2 + nt) * 64 + lane];
    }
    const float b0n0 = cw[B0_OFF + j0];
    const float b0n1 = (j0 < 11) ? cw[B0_OFF + 16 + j0] : 0.f;

    // ---- Stage 1: 4 phases; wave wv owns rows [wv*16, wv*16+16) of each 64-row phase ----
    #pragma unroll
    for (int h = 0; h < 4; ++h) {
        float4* cur = (h & 1) ? ldb : lda;
        float4* nxt = (h & 1) ? lda : ldb;
        if (h < 3) issue(h + 1, nxt);     // next phase's 36KB in flight before this phase's stall
        stage(cur);
        WB();                              // staged tile visible

        const unsigned char* abase = smem + (wv * 16 + j0) * XSTRIDE_B;
        f32x4 acc0 = {0.f, 0.f, 0.f, 0.f};
        f32x4 acc1 = {0.f, 0.f, 0.f, 0.f};
        #pragma unroll
        for (int s = 0; s < 5; ++s) {
            const short8 af = *(const short8*)(abase + s * 64 + g8 * 16);
            acc0 = __builtin_amdgcn_mfma_f32_16x16x32_bf16(af, bfrag[s][0], acc0, 0, 0, 0);
            acc1 = __builtin_amdgcn_mfma_f32_16x16x32_bf16(af, bfrag[s][1], acc1, 0, 0, 0);
        }
        // D layout: col = lane&15, row = (lane>>4)*4 + reg
        #pragma unroll
        for (int r = 0; r < 4; ++r) {
            const int zrow = h * 64 + wv * 16 + g8 * 4 + r;
            const int text = t0 - 4 + zrow;
            const bool okz = (text >= 0 && text < T_);
            zbuf[zrow * ZS_ + j0] = okz ? acc0[r] + b0n0 : 0.f;
            if (j0 < 11)
                zbuf[zrow * ZS_ + 16 + j0] = okz ? acc1[r] + b0n1 : 0.f;
        }
        WB();                              // frag reads + z writes done before next phase's stage()
    }

    // ---- Stage 2: temporal 9-tap mix + bias + leaky relu ----
    const int rows_out = min(TILE_, T_ - t0);
    float oacc[J_];
    if (tid < rows_out) {
        #pragma unroll
        for (int w = 0; w < V_; ++w)
            #pragma unroll
            for (int o2 = 0; o2 < 3; ++o2)
                oacc[w * 3 + o2] = cw[BT_OFF + o2];
        #pragma unroll
        for (int dd = 0; dd < KT_; ++dd) {
            union { f32x4 v4[7]; float f[28]; } zu;
            const f32x4* zp = (const f32x4*)&zbuf[(tid + dd) * ZS_];
            #pragma unroll
            for (int c = 0; c < 7; ++c) zu.v4[c] = zp[c];
            #pragma unroll
            for (int o = 0; o < 3; ++o) {
                #pragma unroll
                for (int o2 = 0; o2 < 3; ++o2) {
                    const float wt = cw[WT_OFF + o * 27 + o2 * 9 + dd];
                    #pragma unroll
                    for (int w = 0; w < V_; ++w)
                        oacc[w * 3 + o2] = fmaf(zu.f[w * 3 + o], wt, oacc[w * 3 + o2]);
                }
            }
        }
        #pragma unroll
        for (int j = 0; j < J_; ++j) oacc[j] = fmaxf(oacc[j], 0.01f * oacc[j]);
    }
    WB();   // stage-2 reads complete
    if (tid < rows_out) {
        #pragma unroll
        for (int j = 0; j < J_; ++j) zbuf[tid * J_ + j] = oacc[j];
    }
    WB();   // repack visible

    const int total4 = (rows_out * J_) / 4;   // 1674 or 432
    float4* dst4 = (float4*)(out + (nrow0 + t0) * J_);
    const float4* src4 = (const float4*)zbuf;
    for (int idx = tid; idx < total4; idx += THREADS_)
        dst4[idx] = src4[idx];
}

extern "C" void kernel_launch(void* const* d_in, const int* in_sizes, int n_in,
                              void* d_out, int out_size, void* d_ws, size_t ws_size,
                              hipStream_t stream) {
    const float* pose = (const float*)d_in[0];
    const float* A    = (const float*)d_in[1];
    const float* Wg   = (const float*)d_in[2];
    const float* bg   = (const float*)d_in[3];
    const float* Wt   = (const float*)d_in[4];
    const float* bt   = (const float*)d_in[5];
    float* ws   = (float*)d_ws;
    float* outp = (float*)d_out;

    setup_weights<<<1, 256, 0, stream>>>(A, Wg, bg, Wt, bt, ws);
    fused_stgcn<<<N_ * NTILE_, THREADS_, 0, stream>>>(pose, ws, outp);
}